// Round 9
// baseline (324.636 us; speedup 1.0000x reference)
//
#include <hip/hip_runtime.h>
#include <stdint.h>

#define NB 2
#define NH 12
#define NS 2048
#define ND 64
#define NT 12   // tiles per persistent WG
#define QR 16   // q rows per tile

typedef __attribute__((ext_vector_type(4))) float f32x4;
typedef __attribute__((ext_vector_type(8))) short s16x8;

__device__ __forceinline__ short f2bf(float x) {
    return __builtin_bit_cast(short, (__bf16)x);
}
__device__ __forceinline__ float bf2f(short h) {
    uint32_t u = ((uint32_t)(unsigned short)h) << 16;
    return __builtin_bit_cast(float, u);
}
__device__ __forceinline__ f32x4 mfma16(s16x8 a, s16x8 b, f32x4 c) {
    return __builtin_amdgcn_mfma_f32_16x16x32_bf16(a, b, c, 0, 0, 0);
}
// LDS-consistent barrier that does NOT drain vmcnt: outstanding global stores
// keep draining across it (T4). sched_barrier fences per rule #18.
__device__ __forceinline__ void ldsbar() {
    asm volatile("s_waitcnt lgkmcnt(0)" ::: "memory");
    __builtin_amdgcn_sched_barrier(0);
    __builtin_amdgcn_s_barrier();
    __builtin_amdgcn_sched_barrier(0);
}

// ---------- pre-pass 1: mask int32 -> bitmask, 1 MB ----------
__global__ void kbits(const int* __restrict__ maskg, uint32_t* __restrict__ bits) {
    int wi = blockIdx.x * 256 + threadIdx.x;
    const int* mp = maskg + (size_t)wi * 32;
    uint32_t v = 0;
#pragma unroll
    for (int i = 0; i < 8; i++) {
        int4 q = *(const int4*)(mp + i * 4);
        v |= ((uint32_t)(q.x != 0) << (i * 4)) | ((uint32_t)(q.y != 0) << (i * 4 + 1)) |
             ((uint32_t)(q.z != 0) << (i * 4 + 2)) | ((uint32_t)(q.w != 0) << (i * 4 + 3));
    }
    bits[wi] = v;
}

// ---------- pre-pass 2: VwT[b,h,d,k] = V[b,h,k,d]*w[k] bf16, 6.3 MB ----------
__global__ void kvwt(const float* __restrict__ Vg, const float* __restrict__ wg,
                     unsigned short* __restrict__ vwt) {
    __shared__ float tile[32][65];
    int blk = blockIdx.x;
    int bh = blk >> 6;
    int k0 = (blk & 63) * 32;
    const float* Vh = Vg + ((size_t)bh * NS + k0) * ND;
    int t = threadIdx.x;
    {
        int kk = t >> 3, c = (t & 7) * 8;
        f32x4 a = *(const f32x4*)(Vh + kk * ND + c);
        f32x4 b4 = *(const f32x4*)(Vh + kk * ND + c + 4);
        float wk = wg[k0 + kk];
#pragma unroll
        for (int j = 0; j < 4; j++) {
            tile[kk][c + j] = a[j] * wk;
            tile[kk][c + 4 + j] = b4[j] * wk;
        }
    }
    __syncthreads();
    {
        int d = t >> 2, kb2 = (t & 3) * 8;
        s16x8 o;
#pragma unroll
        for (int j = 0; j < 8; j++) o[j] = f2bf(tile[kb2 + j][d]);
        *(s16x8*)(vwt + ((size_t)bh * ND + d) * NS + k0 + kb2) = o;
    }
}

// ---------- pre-pass 3: K f32 -> bf16, 6.3 MB ----------
__global__ void kcast(const float* __restrict__ in, unsigned short* __restrict__ outp) {
    size_t t = (size_t)blockIdx.x * 256 + threadIdx.x;
    const float* p = in + t * 8;
    f32x4 a = *(const f32x4*)p;
    f32x4 b = *(const f32x4*)(p + 4);
    s16x8 o;
#pragma unroll
    for (int j = 0; j < 4; j++) {
        o[j] = f2bf(a[j]);
        o[4 + j] = f2bf(b[j]);
    }
    *(s16x8*)(outp + t * 8) = o;
}

// ---------- main: persistent specialized pipeline ----------
// 256 WGs (1/CU), 768 thr = 12 waves, NT=12 tiles of 16 q-rows each.
// LDS: P double-buffer 2 x [16][4096B] bf16 (XOR m<<4) + w[2048] f32 + red/rinv.
// Waves 0-3: PV(t).  Waves 4-7: QK(t+1) (512-k strip each) + ssum partials.
// Waves 8-11: STREAM(t) -- LDS reads + global stores ONLY (never a global
// load, never a vmcnt wait) -> stores stay in flight through the barriers and
// drain continuously while tile t+1 is computed.
__global__ __launch_bounds__(768, 1) void attn_main(
    const float* __restrict__ Qg, const float* __restrict__ wg,
    const uint32_t* __restrict__ bitsg, const unsigned short* __restrict__ vwtg,
    const unsigned short* __restrict__ kbfg, float* __restrict__ outg,
    float* __restrict__ pg) {
    extern __shared__ char smem[];
    float* w_lds = (float*)(smem + 131072);  // 2048 f32 = 8192 B
    float* red = (float*)(smem + 139264);    // [4][16]
    float* rinv = (float*)(smem + 139520);   // [2][16]

    int bid = blockIdx.x;
    // XCD swizzle: 256 WGs = 8 x 32 (bijective). XCD x -> tiles [x*384,+384)
    // = 3 heads -> K+vwt (1.5 MB) stay L2-resident per XCD.
    int g = (bid & 7) * 32 + (bid >> 3);
    int tile0 = g * NT;

    int tid = threadIdx.x;
    int wv = tid >> 6, lane = tid & 63;
    int m = lane & 15, kb = lane >> 4;
    const int xm = m << 4;

    // stage w into LDS (waves 0-3; visible after first ldsbar)
    if (tid < 256) {
        *(f32x4*)(w_lds + tid * 8) = *(const f32x4*)(wg + tid * 8);
        *(f32x4*)(w_lds + tid * 8 + 4) = *(const f32x4*)(wg + tid * 8 + 4);
    }

    // ---- QK: waves 4-7, each owns a 512-k strip of tile `tile` ----
    auto QK = [&](int tile, char* bp) {
        int bh = tile >> 7, q0 = (tile & 127) * QR;
        int b = bh / NH;
        const unsigned short* kbfh = kbfg + (size_t)bh * NS * ND;
        const uint32_t* bitsb =
            bitsg + (size_t)b * (NS * (NS / 32)) + (size_t)(q0 + m) * (NS / 32);
        // Q fragment for this tile (1/8 folded)
        s16x8 qf0, qf1;
        {
            const float* src = Qg + ((size_t)bh * NS + q0 + m) * ND + kb * 8;
            f32x4 a0 = *(const f32x4*)src;
            f32x4 a1 = *(const f32x4*)(src + 4);
            f32x4 b0 = *(const f32x4*)(src + 32);
            f32x4 b1 = *(const f32x4*)(src + 36);
            s16x8 f0, f1;
#pragma unroll
            for (int j = 0; j < 4; j++) {
                f0[j] = f2bf(a0[j] * 0.125f);
                f0[4 + j] = f2bf(a1[j] * 0.125f);
                f1[j] = f2bf(b0[j] * 0.125f);
                f1[4 + j] = f2bf(b1[j] * 0.125f);
            }
            qf0 = f0;
            qf1 = f1;
        }
        float ssum = 0.f;
        const int cb = (wv - 4) * 512;
#pragma unroll 4
        for (int kt = 0; kt < 32; kt++) {
            int krow = cb + kt * 16;
            const unsigned short* kr = kbfh + (size_t)(krow + m) * ND + kb * 8;
            s16x8 kf0 = *(const s16x8*)kr;
            s16x8 kf1 = *(const s16x8*)(kr + 32);
            f32x4 c = {0.f, 0.f, 0.f, 0.f};
            c = mfma16(kf0, qf0, c);
            c = mfma16(kf1, qf1, c);
            int kcol = krow + kb * 4;
            uint32_t keep = bitsb[kcol >> 5] >> (kcol & 31);
            float p0 = ((keep & 1u) && c[0] > 0.f) ? c[0] : 0.f;
            float p1 = ((keep & 2u) && c[1] > 0.f) ? c[1] : 0.f;
            float p2 = ((keep & 4u) && c[2] > 0.f) ? c[2] : 0.f;
            float p3 = ((keep & 8u) && c[3] > 0.f) ? c[3] : 0.f;
            ssum += p0 * p0 + p1 * p1 + p2 * p2 + p3 * p3;
            uint2 u;
            u.x = (uint32_t)(unsigned short)f2bf(p0) |
                  ((uint32_t)(unsigned short)f2bf(p1) << 16);
            u.y = (uint32_t)(unsigned short)f2bf(p2) |
                  ((uint32_t)(unsigned short)f2bf(p3) << 16);
            *(uint2*)(bp + m * 4096 + ((kcol * 2) ^ xm)) = u;
        }
        ssum += __shfl_xor(ssum, 16);
        ssum += __shfl_xor(ssum, 32);
        if (lane < 16) red[(wv - 4) * 16 + lane] = ssum;
    };

    // ---- PV: waves 0-3, own 16-d tile over full k ----
    auto PV = [&](int tile, char* bp, const float* rv) {
        int bh = tile >> 7, q0 = (tile & 127) * QR;
        const unsigned short* vrow = vwtg + ((size_t)bh * ND + wv * 16 + m) * NS;
        f32x4 accA = {0.f, 0.f, 0.f, 0.f}, accB = {0.f, 0.f, 0.f, 0.f};
#pragma unroll 4
        for (int ks = 0; ks < 32; ks++) {
            int k0 = ks * 64;
            s16x8 af0 = *(const s16x8*)(vrow + k0 + kb * 8);
            s16x8 af1 = *(const s16x8*)(vrow + k0 + 32 + kb * 8);
            s16x8 b0 = *(const s16x8*)(bp + m * 4096 + ((k0 * 2 + kb * 16) ^ xm));
            s16x8 b1 = *(const s16x8*)(bp + m * 4096 + ((k0 * 2 + 64 + kb * 16) ^ xm));
            accA = mfma16(af0, b0, accA);
            accB = mfma16(af1, b1, accB);
        }
        float ri = rv[m];
        f32x4 o = {(accA[0] + accB[0]) * ri, (accA[1] + accB[1]) * ri,
                   (accA[2] + accB[2]) * ri, (accA[3] + accB[3]) * ri};
        *(f32x4*)(outg + ((size_t)bh * NS + q0 + m) * ND + wv * 16 + kb * 4) = o;
    };

    // ---- STREAM: waves 8-11, 4 rows each; LDS-only reads, stores only ----
    auto STREAM = [&](int tile, char* bp, const float* rv) {
        int bh = tile >> 7, q0 = (tile & 127) * QR;
        float* ph = pg + ((size_t)bh * NS + q0) * NS;
        int sv = wv - 8;
#pragma unroll
        for (int rr = 0; rr < 4; rr++) {
            int r = sv * 4 + rr;
            float ri = rv[r];
            int xr = r << 4;
#pragma unroll
            for (int it = 0; it < 8; it++) {
                int colf = it * 256 + lane * 4;
                uint2 u = *(const uint2*)(bp + r * 4096 + ((colf * 2) ^ xr));
                f32x4 w4 = *(const f32x4*)(w_lds + colf);
                f32x4 o;
                o[0] = bf2f((short)(u.x & 0xffff)) * w4[0] * ri;
                o[1] = bf2f((short)(u.x >> 16)) * w4[1] * ri;
                o[2] = bf2f((short)(u.y & 0xffff)) * w4[2] * ri;
                o[3] = bf2f((short)(u.y >> 16)) * w4[3] * ri;
                *(f32x4*)(ph + (size_t)r * NS + colf) = o;
            }
        }
    };

    // ---- prologue: QK(tile0) -> buf0; rinv[0] ----
    if (wv >= 4 && wv < 8) QK(tile0, smem);
    ldsbar();
    if (tid < 16) {
        float s = red[tid] + red[16 + tid] + red[32 + tid] + red[48 + tid];
        rinv[tid] = 1.0f / sqrtf(s * (1.0f / NS) + 1e-6f);
    }
    ldsbar();

    // ---- main pipeline: 2 non-draining barriers per tile ----
    for (int lt = 0; lt < NT; lt++) {
        int tile = tile0 + lt;
        char* bp = smem + (size_t)(lt & 1) * 65536;
        const float* rv = rinv + (lt & 1) * 16;
        if (wv < 4) {
            PV(tile, bp, rv);
        } else if (wv < 8) {
            if (lt + 1 < NT) QK(tile + 1, smem + (size_t)((lt + 1) & 1) * 65536);
        } else {
            STREAM(tile, bp, rv);
        }
        ldsbar();
        if (lt + 1 < NT && tid < 16) {
            float s = red[tid] + red[16 + tid] + red[32 + tid] + red[48 + tid];
            rinv[((lt + 1) & 1) * 16 + tid] = 1.0f / sqrtf(s * (1.0f / NS) + 1e-6f);
        }
        ldsbar();
    }
}

// ---------- fallback (no workspace): fp32-exact per-row kernel ----------
__global__ void attn_fallback(const float* __restrict__ Qg, const float* __restrict__ Kg,
                              const float* __restrict__ Vg, const int* __restrict__ maskg,
                              const float* __restrict__ wg, float* __restrict__ outg,
                              float* __restrict__ pg) {
    __shared__ float qs[64];
    __shared__ float srow[2048];
    __shared__ float osum[64];
    __shared__ float red2[8];
    int bid = blockIdx.x;
    int bh = bid >> 11, q = bid & 2047, b = bh / NH;
    int tid = threadIdx.x;
    const float* Qr = Qg + ((size_t)bh * NS + q) * ND;
    const float* Kh = Kg + (size_t)bh * NS * ND;
    const float* Vh = Vg + (size_t)bh * NS * ND;
    const int* mrow = maskg + ((size_t)b * NS + q) * NS;
    if (tid < 64) {
        qs[tid] = Qr[tid] * 0.125f;
        osum[tid] = 0.f;
    }
    __syncthreads();
    float ss = 0.f;
    for (int k = tid; k < NS; k += 256) {
        float s = 0.f;
        const float* kr = Kh + (size_t)k * ND;
        for (int d = 0; d < ND; d++) s += qs[d] * kr[d];
        if (mrow[k] == 0 || s < 0.f) s = 0.f;
        srow[k] = s;
        ss += s * s;
    }
#pragma unroll
    for (int o = 32; o >= 1; o >>= 1) ss += __shfl_down(ss, o);
    if ((tid & 63) == 0) red2[tid >> 6] = ss;
    __syncthreads();
    float ri;
    {
        float tot = red2[0] + red2[1] + red2[2] + red2[3];
        ri = 1.0f / sqrtf(tot * (1.0f / NS) + 1e-6f);
    }
    for (int k = tid; k < NS; k += 256) {
        float pa = srow[k] * ri * wg[k];
        pg[(((size_t)bh * NS + q) * NS) + k] = pa;
        const float* vr = Vh + (size_t)k * ND;
        for (int d = 0; d < ND; d++) atomicAdd(&osum[d], pa * vr[d]);
    }
    __syncthreads();
    if (tid < 64) outg[((size_t)bh * NS + q) * ND + tid] = osum[tid];
}

extern "C" void kernel_launch(void* const* d_in, const int* in_sizes, int n_in,
                              void* d_out, int out_size, void* d_ws, size_t ws_size,
                              hipStream_t stream) {
    const float* Q = (const float*)d_in[0];
    const float* K = (const float*)d_in[1];
    const float* V = (const float*)d_in[2];
    const int* mask = (const int*)d_in[3];
    const float* w = (const float*)d_in[4];
    float* out = (float*)d_out;
    float* pattn = out + (size_t)NB * NH * NS * ND;

    const size_t bits_bytes = (size_t)NB * NS * (NS / 32) * sizeof(uint32_t);     // 1 MB
    const size_t vwt_bytes = (size_t)NB * NH * ND * NS * sizeof(unsigned short);  // 6.3 MB
    const size_t kbf_bytes = vwt_bytes;                                           // 6.3 MB
    const int smem = 131072 + 8192 + 256 + 128;  // 139648 B

    if (ws_size >= bits_bytes + vwt_bytes + kbf_bytes) {
        char* wsb = (char*)d_ws;
        uint32_t* bits = (uint32_t*)wsb;
        unsigned short* vwt = (unsigned short*)(wsb + bits_bytes);
        unsigned short* kbf = (unsigned short*)(wsb + bits_bytes + vwt_bytes);
        kbits<<<(NB * NS * NS / 32) / 256, 256, 0, stream>>>(mask, bits);
        kcast<<<(NB * NH * NS * ND) / (256 * 8), 256, 0, stream>>>(K, kbf);
        kvwt<<<NB * NH * (NS / 32), 256, 0, stream>>>(V, w, vwt);
        hipFuncSetAttribute(reinterpret_cast<const void*>(&attn_main),
                            hipFuncAttributeMaxDynamicSharedMemorySize, smem);
        attn_main<<<256, 768, smem, stream>>>(Q, w, bits, vwt, kbf, out, pattn);
    } else {
        attn_fallback<<<NB * NH * NS, 256, 0, stream>>>(Q, K, V, mask, w, out, pattn);
    }
}

// Round 10
// 244.344 us; speedup vs baseline: 1.3286x; 1.3286x over previous
//
#include <hip/hip_runtime.h>
#include <stdint.h>

#define NB 2
#define NH 12
#define NS 2048
#define ND 64

typedef __attribute__((ext_vector_type(4))) float f32x4;
typedef __attribute__((ext_vector_type(8))) short s16x8;

__device__ __forceinline__ short f2bf(float x) {
    return __builtin_bit_cast(short, (__bf16)x);
}
__device__ __forceinline__ float bf2f(short h) {
    uint32_t u = ((uint32_t)(unsigned short)h) << 16;
    return __builtin_bit_cast(float, u);
}
__device__ __forceinline__ f32x4 mfma16(s16x8 a, s16x8 b, f32x4 c) {
    return __builtin_amdgcn_mfma_f32_16x16x32_bf16(a, b, c, 0, 0, 0);
}

// ---------- pre-pass 1: mask int32 -> bitmask, 1 MB ----------
__global__ void kbits(const int* __restrict__ maskg, uint32_t* __restrict__ bits) {
    int wi = blockIdx.x * 256 + threadIdx.x;
    const int* mp = maskg + (size_t)wi * 32;
    uint32_t v = 0;
#pragma unroll
    for (int i = 0; i < 8; i++) {
        int4 q = *(const int4*)(mp + i * 4);
        v |= ((uint32_t)(q.x != 0) << (i * 4)) | ((uint32_t)(q.y != 0) << (i * 4 + 1)) |
             ((uint32_t)(q.z != 0) << (i * 4 + 2)) | ((uint32_t)(q.w != 0) << (i * 4 + 3));
    }
    bits[wi] = v;
}

// ---------- pre-pass 2: VwT[b,h,d,k] = V[b,h,k,d]*w[k] bf16, 6.3 MB ----------
__global__ void kvwt(const float* __restrict__ Vg, const float* __restrict__ wg,
                     unsigned short* __restrict__ vwt) {
    __shared__ float tile[32][65];
    int blk = blockIdx.x;
    int bh = blk >> 6;
    int k0 = (blk & 63) * 32;
    const float* Vh = Vg + ((size_t)bh * NS + k0) * ND;
    int t = threadIdx.x;
    {
        int kk = t >> 3, c = (t & 7) * 8;
        f32x4 a = *(const f32x4*)(Vh + kk * ND + c);
        f32x4 b4 = *(const f32x4*)(Vh + kk * ND + c + 4);
        float wk = wg[k0 + kk];
#pragma unroll
        for (int j = 0; j < 4; j++) {
            tile[kk][c + j] = a[j] * wk;
            tile[kk][c + 4 + j] = b4[j] * wk;
        }
    }
    __syncthreads();
    {
        int d = t >> 2, kb2 = (t & 3) * 8;
        s16x8 o;
#pragma unroll
        for (int j = 0; j < 8; j++) o[j] = f2bf(tile[kb2 + j][d]);
        *(s16x8*)(vwt + ((size_t)bh * ND + d) * NS + k0 + kb2) = o;
    }
}

// ---------- pre-pass 3: K f32 -> bf16, 6.3 MB ----------
__global__ void kcast(const float* __restrict__ in, unsigned short* __restrict__ outp) {
    size_t t = (size_t)blockIdx.x * 256 + threadIdx.x;
    const float* p = in + t * 8;
    f32x4 a = *(const f32x4*)p;
    f32x4 b = *(const f32x4*)(p + 4);
    s16x8 o;
#pragma unroll
    for (int j = 0; j < 4; j++) {
        o[j] = f2bf(a[j]);
        o[4 + j] = f2bf(b[j]);
    }
    *(s16x8*)(outp + t * 8) = o;
}

// ---------- main: wave-specialized producer/streamer (R8) + NT stores ----------
// WG = 512 thr (8 waves), 16 q-rows. LDS: full P[16][2048] bf16 (64 KB,
// XOR (m&7)<<4) + w copy (8 KB) + reduce scratch. 2 WGs/CU.
// Phase 1 (all 8 waves): QK over own 256-k strip -> relu/mask -> bf16 P in
// LDS + ssum partial. One barrier; rinv.
// Phase 2: waves 0-3: PV MFMA over full k for own 16-d tile -> out; then
// stream 1 p_attn row. Waves 4-7: pure streamers, 3 rows each.
// p_attn stores are NONTEMPORAL: each store instruction covers 1 KB
// contiguous (8 full 128B lines) so early eviction is safe (no RMW), and
// dirty lines stream out of L2 instead of thrashing the K/vwt read set.
__global__ __launch_bounds__(512, 4) void attn_main(
    const float* __restrict__ Qg, const float* __restrict__ wg,
    const uint32_t* __restrict__ bitsg, const unsigned short* __restrict__ vwtg,
    const unsigned short* __restrict__ kbfg, float* __restrict__ outg,
    float* __restrict__ pg) {
    extern __shared__ char smem[];
    char* Pb = smem;                          // [16][4096 B] bf16, 65536 B
    float* w_lds = (float*)(smem + 65536);    // [2048] f32, 8192 B
    float* red = (float*)(smem + 73728);      // [8][16]
    float* rinv_sh = (float*)(smem + 74240);  // [16]

    int bid = blockIdx.x;
    // XCD swizzle: 3072 WGs = 8 x 384 (3 heads per XCD), bijective
    int swz = (bid & 7) * 384 + (bid >> 3);
    int bh = swz >> 7;
    int qb = swz & 127;
    int b = bh / NH;
    int q0 = qb * 16;

    const unsigned short* kbfh = kbfg + (size_t)bh * NS * ND;
    const uint32_t* bitsb = bitsg + (size_t)b * (NS * (NS / 32));
    float* ph = pg + ((size_t)bh * NS + q0) * NS;
    float* outh = outg + (size_t)bh * NS * ND;

    int tid = threadIdx.x;
    int wv = tid >> 6, lane = tid & 63;
    int m = lane & 15, kb = lane >> 4;
    const int xm = (m & 7) << 4;

    // stage w into LDS (visible after the rms barrier)
    *(f32x4*)(w_lds + tid * 4) = *(const f32x4*)(wg + tid * 4);

    // Q fragments (B operand), 1/8 folded
    s16x8 qf[2];
#pragma unroll
    for (int ks = 0; ks < 2; ks++) {
        const float* src = Qg + ((size_t)bh * NS + q0 + m) * ND + ks * 32 + kb * 8;
        f32x4 a = *(const f32x4*)src;
        f32x4 c4 = *(const f32x4*)(src + 4);
        s16x8 f;
#pragma unroll
        for (int j = 0; j < 4; j++) {
            f[j] = f2bf(a[j] * 0.125f);
            f[4 + j] = f2bf(c4[j] * 0.125f);
        }
        qf[ks] = f;
    }

    // ---- Phase 1: QK over this wave's 256-k strip -> P (LDS) + ssum ----
    float ssum = 0.f;
    const int cbase = wv * 256;
#pragma unroll 4
    for (int kt = 0; kt < 16; kt++) {
        int krow = cbase + kt * 16;
        s16x8 kf0 = *(const s16x8*)(kbfh + (size_t)(krow + m) * ND + kb * 8);
        s16x8 kf1 = *(const s16x8*)(kbfh + (size_t)(krow + m) * ND + 32 + kb * 8);
        f32x4 c = {0.f, 0.f, 0.f, 0.f};
        c = mfma16(kf0, qf[0], c);
        c = mfma16(kf1, qf[1], c);
        int kcol = krow + kb * 4;
        uint32_t word = bitsb[(size_t)(q0 + m) * (NS / 32) + (kcol >> 5)];
        uint32_t keepbits = word >> (kcol & 31);
        float p[4];
#pragma unroll
        for (int r = 0; r < 4; r++) {
            float s = c[r];
            bool keep = ((keepbits >> r) & 1u) && (s > 0.f);
            p[r] = keep ? s : 0.f;
            ssum += p[r] * p[r];
        }
        uint2 u;
        u.x = (uint32_t)(unsigned short)f2bf(p[0]) |
              ((uint32_t)(unsigned short)f2bf(p[1]) << 16);
        u.y = (uint32_t)(unsigned short)f2bf(p[2]) |
              ((uint32_t)(unsigned short)f2bf(p[3]) << 16);
        *(uint2*)(Pb + m * 4096 + ((kcol * 2) ^ xm)) = u;
    }
    ssum += __shfl_xor(ssum, 16);
    ssum += __shfl_xor(ssum, 32);
    if (lane < 16) red[wv * 16 + lane] = ssum;
    __syncthreads();
    if (tid < 16) {
        float s = 0.f;
#pragma unroll
        for (int i = 0; i < 8; i++) s += red[i * 16 + tid];
        rinv_sh[tid] = 1.0f / sqrtf(s * (1.0f / NS) + 1e-6f);
    }
    __syncthreads();

    // stream one p_attn row: LDS reads + pure NT global stores
    auto stream_row = [&](int r) {
        float ri = rinv_sh[r];
        int xr = (r & 7) << 4;
#pragma unroll
        for (int it = 0; it < 8; it++) {
            int colf = it * 256 + lane * 4;
            uint2 u = *(const uint2*)(Pb + r * 4096 + ((colf * 2) ^ xr));
            f32x4 w4 = *(const f32x4*)(w_lds + colf);
            f32x4 o;
            o[0] = bf2f((short)(u.x & 0xffff)) * w4[0] * ri;
            o[1] = bf2f((short)(u.x >> 16)) * w4[1] * ri;
            o[2] = bf2f((short)(u.y & 0xffff)) * w4[2] * ri;
            o[3] = bf2f((short)(u.y >> 16)) * w4[3] * ri;
            __builtin_nontemporal_store(o, (f32x4*)(ph + (size_t)r * NS + colf));
        }
    };

    // ---- Phase 2 ----
    if (wv < 4) {
        // PV: this wave owns d-tile [dt*16, +16) over ALL k; two acc chains
        const int dt = wv;
        const unsigned short* vrow = vwtg + ((size_t)bh * ND + dt * 16 + m) * NS;
        f32x4 accA = {0.f, 0.f, 0.f, 0.f}, accB = {0.f, 0.f, 0.f, 0.f};
#pragma unroll 4
        for (int ks = 0; ks < 32; ks++) {
            int k0 = ks * 64;
            s16x8 af0 = *(const s16x8*)(vrow + k0 + kb * 8);
            s16x8 af1 = *(const s16x8*)(vrow + k0 + 32 + kb * 8);
            s16x8 b0 = *(const s16x8*)(Pb + m * 4096 + ((k0 * 2 + kb * 16) ^ xm));
            s16x8 b1 = *(const s16x8*)(Pb + m * 4096 + (((k0 + 32) * 2 + kb * 16) ^ xm));
            accA = mfma16(af0, b0, accA);
            accB = mfma16(af1, b1, accB);
        }
        float ri = rinv_sh[m];
        f32x4 o = {(accA[0] + accB[0]) * ri, (accA[1] + accB[1]) * ri,
                   (accA[2] + accB[2]) * ri, (accA[3] + accB[3]) * ri};
        __builtin_nontemporal_store(o,
                                    (f32x4*)(outh + (size_t)(q0 + m) * ND + dt * 16 + kb * 4));
        // then help stream: one row
        stream_row(12 + wv);
    } else {
        // PURE STREAMER: 3 rows, no global loads ever
        int sv = wv - 4;
        stream_row(sv * 3);
        stream_row(sv * 3 + 1);
        stream_row(sv * 3 + 2);
    }
}

// ---------- fallback (no workspace): fp32-exact per-row kernel ----------
__global__ void attn_fallback(const float* __restrict__ Qg, const float* __restrict__ Kg,
                              const float* __restrict__ Vg, const int* __restrict__ maskg,
                              const float* __restrict__ wg, float* __restrict__ outg,
                              float* __restrict__ pg) {
    __shared__ float qs[64];
    __shared__ float srow[2048];
    __shared__ float osum[64];
    __shared__ float red2[8];
    int bid = blockIdx.x;
    int bh = bid >> 11, q = bid & 2047, b = bh / NH;
    int tid = threadIdx.x;
    const float* Qr = Qg + ((size_t)bh * NS + q) * ND;
    const float* Kh = Kg + (size_t)bh * NS * ND;
    const float* Vh = Vg + (size_t)bh * NS * ND;
    const int* mrow = maskg + ((size_t)b * NS + q) * NS;
    if (tid < 64) {
        qs[tid] = Qr[tid] * 0.125f;
        osum[tid] = 0.f;
    }
    __syncthreads();
    float ss = 0.f;
    for (int k = tid; k < NS; k += 256) {
        float s = 0.f;
        const float* kr = Kh + (size_t)k * ND;
        for (int d = 0; d < ND; d++) s += qs[d] * kr[d];
        if (mrow[k] == 0 || s < 0.f) s = 0.f;
        srow[k] = s;
        ss += s * s;
    }
#pragma unroll
    for (int o = 32; o >= 1; o >>= 1) ss += __shfl_down(ss, o);
    if ((tid & 63) == 0) red2[tid >> 6] = ss;
    __syncthreads();
    float ri;
    {
        float tot = red2[0] + red2[1] + red2[2] + red2[3];
        ri = 1.0f / sqrtf(tot * (1.0f / NS) + 1e-6f);
    }
    for (int k = tid; k < NS; k += 256) {
        float pa = srow[k] * ri * wg[k];
        pg[(((size_t)bh * NS + q) * NS) + k] = pa;
        const float* vr = Vh + (size_t)k * ND;
        for (int d = 0; d < ND; d++) atomicAdd(&osum[d], pa * vr[d]);
    }
    __syncthreads();
    if (tid < 64) outg[((size_t)bh * NS + q) * ND + tid] = osum[tid];
}

extern "C" void kernel_launch(void* const* d_in, const int* in_sizes, int n_in,
                              void* d_out, int out_size, void* d_ws, size_t ws_size,
                              hipStream_t stream) {
    const float* Q = (const float*)d_in[0];
    const float* K = (const float*)d_in[1];
    const float* V = (const float*)d_in[2];
    const int* mask = (const int*)d_in[3];
    const float* w = (const float*)d_in[4];
    float* out = (float*)d_out;
    float* pattn = out + (size_t)NB * NH * NS * ND;

    const size_t bits_bytes = (size_t)NB * NS * (NS / 32) * sizeof(uint32_t);     // 1 MB
    const size_t vwt_bytes = (size_t)NB * NH * ND * NS * sizeof(unsigned short);  // 6.3 MB
    const size_t kbf_bytes = vwt_bytes;                                           // 6.3 MB
    const int nwg = NB * NH * (NS / 16);  // 3072
    const int smem = 65536 + 8192 + 512 + 64;  // 74304 B

    if (ws_size >= bits_bytes + vwt_bytes + kbf_bytes) {
        char* wsb = (char*)d_ws;
        uint32_t* bits = (uint32_t*)wsb;
        unsigned short* vwt = (unsigned short*)(wsb + bits_bytes);
        unsigned short* kbf = (unsigned short*)(wsb + bits_bytes + vwt_bytes);
        kbits<<<(NB * NS * NS / 32) / 256, 256, 0, stream>>>(mask, bits);
        kcast<<<(NB * NH * NS * ND) / (256 * 8), 256, 0, stream>>>(K, kbf);
        kvwt<<<NB * NH * (NS / 32), 256, 0, stream>>>(V, w, vwt);
        hipFuncSetAttribute(reinterpret_cast<const void*>(&attn_main),
                            hipFuncAttributeMaxDynamicSharedMemorySize, smem);
        attn_main<<<nwg, 512, smem, stream>>>(Q, w, bits, vwt, kbf, out, pattn);
    } else {
        attn_fallback<<<NB * NH * NS, 256, 0, stream>>>(Q, K, V, mask, w, out, pattn);
    }
}

// Round 11
// 189.494 us; speedup vs baseline: 1.7132x; 1.2895x over previous
//
#include <hip/hip_runtime.h>
#include <stdint.h>

#define NB 2
#define NH 12
#define NS 2048
#define ND 64

typedef __attribute__((ext_vector_type(4))) float f32x4;
typedef __attribute__((ext_vector_type(8))) short s16x8;

__device__ __forceinline__ short f2bf(float x) {
    return __builtin_bit_cast(short, (__bf16)x);
}
__device__ __forceinline__ float bf2f(short h) {
    uint32_t u = ((uint32_t)(unsigned short)h) << 16;
    return __builtin_bit_cast(float, u);
}
__device__ __forceinline__ f32x4 mfma16(s16x8 a, s16x8 b, f32x4 c) {
    return __builtin_amdgcn_mfma_f32_16x16x32_bf16(a, b, c, 0, 0, 0);
}

// ---------- pre-pass 1: mask int32 -> bitmask, 1 MB ----------
__global__ void kbits(const int* __restrict__ maskg, uint32_t* __restrict__ bits) {
    int wi = blockIdx.x * 256 + threadIdx.x;
    const int* mp = maskg + (size_t)wi * 32;
    uint32_t v = 0;
#pragma unroll
    for (int i = 0; i < 8; i++) {
        int4 q = *(const int4*)(mp + i * 4);
        v |= ((uint32_t)(q.x != 0) << (i * 4)) | ((uint32_t)(q.y != 0) << (i * 4 + 1)) |
             ((uint32_t)(q.z != 0) << (i * 4 + 2)) | ((uint32_t)(q.w != 0) << (i * 4 + 3));
    }
    bits[wi] = v;
}

// ---------- pre-pass 2: VwT[b,h,d,k] = V[b,h,k,d]*w[k] bf16, 6.3 MB ----------
__global__ void kvwt(const float* __restrict__ Vg, const float* __restrict__ wg,
                     unsigned short* __restrict__ vwt) {
    __shared__ float tile[32][65];
    int blk = blockIdx.x;
    int bh = blk >> 6;
    int k0 = (blk & 63) * 32;
    const float* Vh = Vg + ((size_t)bh * NS + k0) * ND;
    int t = threadIdx.x;
    {
        int kk = t >> 3, c = (t & 7) * 8;
        f32x4 a = *(const f32x4*)(Vh + kk * ND + c);
        f32x4 b4 = *(const f32x4*)(Vh + kk * ND + c + 4);
        float wk = wg[k0 + kk];
#pragma unroll
        for (int j = 0; j < 4; j++) {
            tile[kk][c + j] = a[j] * wk;
            tile[kk][c + 4 + j] = b4[j] * wk;
        }
    }
    __syncthreads();
    {
        int d = t >> 2, kb2 = (t & 3) * 8;
        s16x8 o;
#pragma unroll
        for (int j = 0; j < 8; j++) o[j] = f2bf(tile[kb2 + j][d]);
        *(s16x8*)(vwt + ((size_t)bh * ND + d) * NS + k0 + kb2) = o;
    }
}

// ---------- pre-pass 3: K f32 -> bf16, 6.3 MB ----------
__global__ void kcast(const float* __restrict__ in, unsigned short* __restrict__ outp) {
    size_t t = (size_t)blockIdx.x * 256 + threadIdx.x;
    const float* p = in + t * 8;
    f32x4 a = *(const f32x4*)p;
    f32x4 b = *(const f32x4*)(p + 4);
    s16x8 o;
#pragma unroll
    for (int j = 0; j < 4; j++) {
        o[j] = f2bf(a[j]);
        o[4 + j] = f2bf(b[j]);
    }
    *(s16x8*)(outp + t * 8) = o;
}

// ---------- main: 32-row tiles, 16 waves, specialized phase 2 ----------
// WG = 1024 thr (16 waves), 32 q-rows, 1 WG/CU (138 KB LDS).
// Rationale: 32-row tiles HALVE the chip-wide K + VwT L2 read volume
// (1.58 GB -> 0.79 GB) that contends with the 402 MB p_attn store stream in
// the per-XCD L2s (the R8/R10 stall was load-wait under store pressure).
// Phase 1 (read-only): all 16 waves QK their 128-k strip -> bf16 P in LDS
// (XOR (q&7)<<4) + ssum. Barrier; rinv; barrier.
// Phase 2: waves 0-3 PV (own 16-d tile, full k; vwt read ONCE per WG for 32
// rows); waves 4-15 pure streamers (LDS reads + NT stores only).
__global__ __launch_bounds__(1024, 4) void attn_main(
    const float* __restrict__ Qg, const float* __restrict__ wg,
    const uint32_t* __restrict__ bitsg, const unsigned short* __restrict__ vwtg,
    const unsigned short* __restrict__ kbfg, float* __restrict__ outg,
    float* __restrict__ pg) {
    extern __shared__ char smem[];
    char* Pb = smem;                           // [32][4096 B] bf16 = 131072
    float* w_lds = (float*)(smem + 131072);    // [2048] f32 = 8192
    float* red = (float*)(smem + 139264);      // [16][32] = 2048
    float* rinv_sh = (float*)(smem + 141312);  // [32] = 128

    int bid = blockIdx.x;
    // XCD swizzle: 1536 WGs = 8 x 192 (bijective); 192 WGs = 1.5 heads/XCD ->
    // K+vwt working set ~768 KB, L2-resident.
    int swz = (bid & 7) * 192 + (bid >> 3);
    int bh = swz >> 6;
    int qb = swz & 63;
    int b = bh / NH;
    int q0 = qb * 32;

    const unsigned short* kbfh = kbfg + (size_t)bh * NS * ND;
    const uint32_t* bitsb = bitsg + (size_t)b * (NS * (NS / 32));
    float* ph = pg + ((size_t)bh * NS + q0) * NS;
    float* outh = outg + (size_t)bh * NS * ND;

    int tid = threadIdx.x;
    int wv = tid >> 6, lane = tid & 63;
    int m = lane & 15, kb = lane >> 4;
    const int xm = (m & 7) << 4;  // == (q&7)<<4 for q = n*16+m

    // stage w into LDS (visible after rms barrier)
    if (tid < 512) *(f32x4*)(w_lds + tid * 4) = *(const f32x4*)(wg + tid * 4);

    // Q fragments for both 16-row groups (1/8 folded)
    s16x8 qf[2][2];
#pragma unroll
    for (int n = 0; n < 2; n++)
#pragma unroll
        for (int ks = 0; ks < 2; ks++) {
            const float* src = Qg + ((size_t)bh * NS + q0 + n * 16 + m) * ND + ks * 32 + kb * 8;
            f32x4 a = *(const f32x4*)src;
            f32x4 c4 = *(const f32x4*)(src + 4);
            s16x8 f;
#pragma unroll
            for (int j = 0; j < 4; j++) {
                f[j] = f2bf(a[j] * 0.125f);
                f[4 + j] = f2bf(c4[j] * 0.125f);
            }
            qf[n][ks] = f;
        }

    // ---- Phase 1: all 16 waves QK own 128-k strip (read-only globals) ----
    float ssum[2] = {0.f, 0.f};
    const int cbase = wv * 128;
#pragma unroll 4
    for (int kt = 0; kt < 8; kt++) {
        int krow = cbase + kt * 16;
        const unsigned short* kr = kbfh + (size_t)(krow + m) * ND + kb * 8;
        s16x8 kf0 = *(const s16x8*)kr;
        s16x8 kf1 = *(const s16x8*)(kr + 32);
        f32x4 c0 = {0.f, 0.f, 0.f, 0.f}, c1 = {0.f, 0.f, 0.f, 0.f};
        c0 = mfma16(kf0, qf[0][0], c0);
        c0 = mfma16(kf1, qf[0][1], c0);
        c1 = mfma16(kf0, qf[1][0], c1);
        c1 = mfma16(kf1, qf[1][1], c1);
        int kcol = krow + kb * 4;
#pragma unroll
        for (int n = 0; n < 2; n++) {
            f32x4 c = n ? c1 : c0;
            int q = n * 16 + m;
            uint32_t word = bitsb[(size_t)(q0 + q) * (NS / 32) + (kcol >> 5)];
            uint32_t keepbits = word >> (kcol & 31);
            float p[4];
#pragma unroll
            for (int r = 0; r < 4; r++) {
                float s = c[r];
                bool keep = ((keepbits >> r) & 1u) && (s > 0.f);
                p[r] = keep ? s : 0.f;
                ssum[n] += p[r] * p[r];
            }
            uint2 u;
            u.x = (uint32_t)(unsigned short)f2bf(p[0]) |
                  ((uint32_t)(unsigned short)f2bf(p[1]) << 16);
            u.y = (uint32_t)(unsigned short)f2bf(p[2]) |
                  ((uint32_t)(unsigned short)f2bf(p[3]) << 16);
            *(uint2*)(Pb + q * 4096 + ((kcol * 2) ^ xm)) = u;
        }
    }
    ssum[0] += __shfl_xor(ssum[0], 16);
    ssum[0] += __shfl_xor(ssum[0], 32);
    ssum[1] += __shfl_xor(ssum[1], 16);
    ssum[1] += __shfl_xor(ssum[1], 32);
    if (lane < 16) {
        red[wv * 32 + lane] = ssum[0];
        red[wv * 32 + 16 + lane] = ssum[1];
    }
    __syncthreads();
    if (tid < 32) {
        float s = 0.f;
#pragma unroll
        for (int i = 0; i < 16; i++) s += red[i * 32 + tid];
        rinv_sh[tid] = 1.0f / sqrtf(s * (1.0f / NS) + 1e-6f);
    }
    __syncthreads();

    // ---- Phase 2 ----
    if (wv < 4) {
        // PV: wave owns d-tile dt over all 32 rows; vwt read once per WG
        const int dt = wv;
        const unsigned short* vrow = vwtg + ((size_t)bh * ND + dt * 16 + m) * NS;
        f32x4 acc[2][2];
#pragma unroll
        for (int n = 0; n < 2; n++)
#pragma unroll
            for (int h = 0; h < 2; h++) acc[n][h] = (f32x4){0.f, 0.f, 0.f, 0.f};
#pragma unroll 4
        for (int ks = 0; ks < 32; ks++) {
            int k0 = ks * 64;
            s16x8 af0 = *(const s16x8*)(vrow + k0 + kb * 8);
            s16x8 af1 = *(const s16x8*)(vrow + k0 + 32 + kb * 8);
#pragma unroll
            for (int n = 0; n < 2; n++) {
                int q = n * 16 + m;
                s16x8 b0 = *(const s16x8*)(Pb + q * 4096 + ((k0 * 2 + kb * 16) ^ xm));
                s16x8 b1 = *(const s16x8*)(Pb + q * 4096 + ((k0 * 2 + 64 + kb * 16) ^ xm));
                acc[n][0] = mfma16(af0, b0, acc[n][0]);
                acc[n][1] = mfma16(af1, b1, acc[n][1]);
            }
        }
#pragma unroll
        for (int n = 0; n < 2; n++) {
            int q = n * 16 + m;
            float ri = rinv_sh[q];
            f32x4 o = {(acc[n][0][0] + acc[n][1][0]) * ri, (acc[n][0][1] + acc[n][1][1]) * ri,
                       (acc[n][0][2] + acc[n][1][2]) * ri, (acc[n][0][3] + acc[n][1][3]) * ri};
            __builtin_nontemporal_store(
                o, (f32x4*)(outh + (size_t)(q0 + q) * ND + dt * 16 + kb * 4));
        }
    } else {
        // PURE STREAMERS: 12 waves, rows strided by 12; LDS reads + NT stores
        for (int r = wv - 4; r < 32; r += 12) {
            float ri = rinv_sh[r];
            int xr = (r & 7) << 4;
#pragma unroll
            for (int it = 0; it < 8; it++) {
                int colf = it * 256 + lane * 4;
                uint2 u = *(const uint2*)(Pb + r * 4096 + ((colf * 2) ^ xr));
                f32x4 w4 = *(const f32x4*)(w_lds + colf);
                f32x4 o;
                o[0] = bf2f((short)(u.x & 0xffff)) * w4[0] * ri;
                o[1] = bf2f((short)(u.x >> 16)) * w4[1] * ri;
                o[2] = bf2f((short)(u.y & 0xffff)) * w4[2] * ri;
                o[3] = bf2f((short)(u.y >> 16)) * w4[3] * ri;
                __builtin_nontemporal_store(o, (f32x4*)(ph + (size_t)r * NS + colf));
            }
        }
    }
}

// ---------- fallback (no workspace): fp32-exact per-row kernel ----------
__global__ void attn_fallback(const float* __restrict__ Qg, const float* __restrict__ Kg,
                              const float* __restrict__ Vg, const int* __restrict__ maskg,
                              const float* __restrict__ wg, float* __restrict__ outg,
                              float* __restrict__ pg) {
    __shared__ float qs[64];
    __shared__ float srow[2048];
    __shared__ float osum[64];
    __shared__ float red2[8];
    int bid = blockIdx.x;
    int bh = bid >> 11, q = bid & 2047, b = bh / NH;
    int tid = threadIdx.x;
    const float* Qr = Qg + ((size_t)bh * NS + q) * ND;
    const float* Kh = Kg + (size_t)bh * NS * ND;
    const float* Vh = Vg + (size_t)bh * NS * ND;
    const int* mrow = maskg + ((size_t)b * NS + q) * NS;
    if (tid < 64) {
        qs[tid] = Qr[tid] * 0.125f;
        osum[tid] = 0.f;
    }
    __syncthreads();
    float ss = 0.f;
    for (int k = tid; k < NS; k += 256) {
        float s = 0.f;
        const float* kr = Kh + (size_t)k * ND;
        for (int d = 0; d < ND; d++) s += qs[d] * kr[d];
        if (mrow[k] == 0 || s < 0.f) s = 0.f;
        srow[k] = s;
        ss += s * s;
    }
#pragma unroll
    for (int o = 32; o >= 1; o >>= 1) ss += __shfl_down(ss, o);
    if ((tid & 63) == 0) red2[tid >> 6] = ss;
    __syncthreads();
    float ri;
    {
        float tot = red2[0] + red2[1] + red2[2] + red2[3];
        ri = 1.0f / sqrtf(tot * (1.0f / NS) + 1e-6f);
    }
    for (int k = tid; k < NS; k += 256) {
        float pa = srow[k] * ri * wg[k];
        pg[(((size_t)bh * NS + q) * NS) + k] = pa;
        const float* vr = Vh + (size_t)k * ND;
        for (int d = 0; d < ND; d++) atomicAdd(&osum[d], pa * vr[d]);
    }
    __syncthreads();
    if (tid < 64) outg[((size_t)bh * NS + q) * ND + tid] = osum[tid];
}

extern "C" void kernel_launch(void* const* d_in, const int* in_sizes, int n_in,
                              void* d_out, int out_size, void* d_ws, size_t ws_size,
                              hipStream_t stream) {
    const float* Q = (const float*)d_in[0];
    const float* K = (const float*)d_in[1];
    const float* V = (const float*)d_in[2];
    const int* mask = (const int*)d_in[3];
    const float* w = (const float*)d_in[4];
    float* out = (float*)d_out;
    float* pattn = out + (size_t)NB * NH * NS * ND;

    const size_t bits_bytes = (size_t)NB * NS * (NS / 32) * sizeof(uint32_t);     // 1 MB
    const size_t vwt_bytes = (size_t)NB * NH * ND * NS * sizeof(unsigned short);  // 6.3 MB
    const size_t kbf_bytes = vwt_bytes;                                           // 6.3 MB
    const int nwg = NB * NH * (NS / 32);  // 1536
    const int smem = 131072 + 8192 + 2048 + 128;  // 141440 B

    if (ws_size >= bits_bytes + vwt_bytes + kbf_bytes) {
        char* wsb = (char*)d_ws;
        uint32_t* bits = (uint32_t*)wsb;
        unsigned short* vwt = (unsigned short*)(wsb + bits_bytes);
        unsigned short* kbf = (unsigned short*)(wsb + bits_bytes + vwt_bytes);
        kbits<<<(NB * NS * NS / 32) / 256, 256, 0, stream>>>(mask, bits);
        kcast<<<(NB * NH * NS * ND) / (256 * 8), 256, 0, stream>>>(K, kbf);
        kvwt<<<NB * NH * (NS / 32), 256, 0, stream>>>(V, w, vwt);
        hipFuncSetAttribute(reinterpret_cast<const void*>(&attn_main),
                            hipFuncAttributeMaxDynamicSharedMemorySize, smem);
        attn_main<<<nwg, 1024, smem, stream>>>(Q, w, bits, vwt, kbf, out, pattn);
    } else {
        attn_fallback<<<NB * NH * NS, 256, 0, stream>>>(Q, K, V, mask, w, out, pattn);
    }
}